// Round 1
// baseline (2887.606 us; speedup 1.0000x reference)
//
#include <hip/hip_runtime.h>
#include <stdint.h>

typedef unsigned short u16;
typedef unsigned int u32;
typedef __attribute__((ext_vector_type(8))) short short8;
typedef __attribute__((ext_vector_type(4))) float floatx4;

#define DIM 128
#define DIM2 64   // h dwords per row (2 bf16 per dword)
#define NBK 1024  // scan width (max buckets); B = ceil(N/128) = 782 for N=100000
#define NB_SH 7   // 128 nodes per bucket
#define AGG_NB 128
#define SC_C 4096  // edges per scatter/hist workgroup chunk

__device__ __forceinline__ u32 f32_to_bf16_rne(float f) {
  u32 u = __float_as_uint(f);
  u32 r = u + 0x7fffu + ((u >> 16) & 1u);
  return r >> 16;
}
__device__ __forceinline__ float bf16_to_f32(u32 u) { return __uint_as_float(u << 16); }
__device__ __forceinline__ u32 pack2bf16(float a, float b) {
  return f32_to_bf16_rne(a) | (f32_to_bf16_rne(b) << 16);
}

union FragU {
  u32 d[4];
  short8 s;
};

// h = x @ W^T via bf16 MFMA (unchanged from R8; frag maps verified m89/m120).
__global__ __launch_bounds__(256) void gemm_mfma(const float* __restrict__ x,
                                                 const float* __restrict__ W,
                                                 u16* __restrict__ h, int N) {
  __shared__ u32 Wl[DIM * DIM2];  // 32 KB
  int tid = threadIdx.x;
#pragma unroll
  for (int i = 0; i < 8; ++i) {
    int ga = tid + 256 * i;
    int o = ga >> 4, g = ga & 15;
    const float* src = W + (size_t)o * DIM + g * 8;
    floatx4 f0 = *(const floatx4*)src;
    floatx4 f1 = *(const floatx4*)(src + 4);
    int slot = (g + o) & 15;
    u32* dst = &Wl[o * DIM2 + slot * 4];
    dst[0] = pack2bf16(f0.x, f0.y);
    dst[1] = pack2bf16(f0.z, f0.w);
    dst[2] = pack2bf16(f1.x, f1.y);
    dst[3] = pack2bf16(f1.z, f1.w);
  }
  __syncthreads();

  int lane = tid & 63;
  int wave = tid >> 6;
  int nodeBase = (blockIdx.x * 4 + wave) * 16;
  if (nodeBase >= N) return;
  int m = lane & 15;
  int kg = lane >> 4;

  short8 a[4];
  const float* xr = x + (size_t)(nodeBase + m) * DIM + kg * 8;
#pragma unroll
  for (int kt = 0; kt < 4; ++kt) {
    floatx4 f0 = *(const floatx4*)(xr + kt * 32);
    floatx4 f1 = *(const floatx4*)(xr + kt * 32 + 4);
    FragU fu;
    fu.d[0] = pack2bf16(f0.x, f0.y);
    fu.d[1] = pack2bf16(f0.z, f0.w);
    fu.d[2] = pack2bf16(f1.x, f1.y);
    fu.d[3] = pack2bf16(f1.z, f1.w);
    a[kt] = fu.s;
  }

#pragma unroll
  for (int ot = 0; ot < 8; ++ot) {
    int o = ot * 16 + m;
    floatx4 acc = {0.f, 0.f, 0.f, 0.f};
#pragma unroll
    for (int kt = 0; kt < 4; ++kt) {
      int slot = (kt * 4 + kg + o) & 15;
      short8 b = *(short8*)&Wl[o * DIM2 + slot * 4];
      acc = __builtin_amdgcn_mfma_f32_16x16x32_bf16(a[kt], b, acc, 0, 0, 0);
    }
#pragma unroll
    for (int r = 0; r < 4; ++r) {
      int node = nodeBase + kg * 4 + r;
      h[(size_t)node * DIM + ot * 16 + m] = (u16)f32_to_bf16_rne(acc[r]);
    }
  }
}

__global__ void zero_kernel(int* __restrict__ p, int n) {
  int i = blockIdx.x * blockDim.x + threadIdx.x;
  if (i < n) p[i] = 0;
}

// Exclusive scan over 1024 LDS counters with 256 threads (4 contiguous per thread).
// Caller must __syncthreads() before. Leaves excl[] valid for all threads on exit.
__device__ __forceinline__ void scan1024(u32* cnt, u32* excl, u32* wtot) {
  int tid = threadIdx.x, lane = tid & 63, wave = tid >> 6;
  u32 c0 = cnt[tid * 4 + 0], c1 = cnt[tid * 4 + 1];
  u32 c2 = cnt[tid * 4 + 2], c3 = cnt[tid * 4 + 3];
  u32 sum = c0 + c1 + c2 + c3;
  u32 inc = sum;
#pragma unroll
  for (int d = 1; d < 64; d <<= 1) {
    u32 t = __shfl_up(inc, d, 64);
    if (lane >= d) inc += t;
  }
  if (lane == 63) wtot[wave] = inc;
  __syncthreads();
  u32 wbase = 0;
  for (int w = 0; w < wave; ++w) wbase += wtot[w];
  u32 run = wbase + inc - sum;
  excl[tid * 4 + 0] = run; run += c0;
  excl[tid * 4 + 1] = run; run += c1;
  excl[tid * 4 + 2] = run; run += c2;
  excl[tid * 4 + 3] = run;
  __syncthreads();
}

// Global bucket histogram: LDS pre-aggregation, one global atomic per (WG,bucket).
__global__ __launch_bounds__(256) void bucket_hist(const int* __restrict__ rows,
                                                   int* __restrict__ bhist, int E, int B) {
  __shared__ u32 hist[NBK];
  int tid = threadIdx.x;
  for (int b = tid; b < NBK; b += 256) hist[b] = 0;
  __syncthreads();
  int base = blockIdx.x * SC_C;
  for (int j = tid; j < SC_C; j += 256) {
    int e = base + j;
    if (e < E) atomicAdd(&hist[((u32)rows[e]) >> NB_SH], 1u);
  }
  __syncthreads();
  for (int b = tid; b < B; b += 256) {
    u32 c = hist[b];
    if (c) atomicAdd(&bhist[b], (int)c);
  }
}

// One-WG exclusive scan of bucket counts -> bbase (agg reads) and bptr (scatter bumps).
__global__ __launch_bounds__(256) void bucket_scan(const int* __restrict__ bhist,
                                                   int* __restrict__ bbase,
                                                   int* __restrict__ bptr) {
  __shared__ u32 cnt[NBK], excl[NBK], wtot[4];
  int tid = threadIdx.x;
  for (int b = tid; b < NBK; b += 256) cnt[b] = (u32)bhist[b];
  __syncthreads();
  scan1024(cnt, excl, wtot);
  for (int b = tid; b < NBK; b += 256) {
    bbase[b] = (int)excl[b];
    bptr[b] = (int)excl[b];
  }
}

// LDS-binned scatter: stage 4096 records grouped by bucket in LDS, flush as
// near-coalesced runs (avg run ~5 records). Replaces the 15x-write-amplified
// per-node scatter (297 MB -> ~compulsory).
__global__ __launch_bounds__(256) void bin_scatter(const int* __restrict__ rows,
                                                   const int* __restrict__ cols,
                                                   const float* __restrict__ vals,
                                                   int* __restrict__ bptr,
                                                   u32* __restrict__ bcol,
                                                   u16* __restrict__ bval, int E) {
  __shared__ u32 hist[NBK], starts[NBK], roff[NBK], gbase[NBK], wtot[4];
  __shared__ u32 s_col[SC_C];
  __shared__ u16 s_val[SC_C];
  __shared__ u16 s_bkt[SC_C];
  int tid = threadIdx.x;
  int base = blockIdx.x * SC_C;
  int tot = min(SC_C, E - base);

  for (int b = tid; b < NBK; b += 256) hist[b] = 0;
  __syncthreads();
  // pass 1: local histogram
  for (int j = tid; j < tot; j += 256) {
    atomicAdd(&hist[((u32)rows[base + j]) >> NB_SH], 1u);
  }
  __syncthreads();
  scan1024(hist, starts, wtot);
  // reserve global space per bucket; init running offsets
  for (int b = tid; b < NBK; b += 256) {
    u32 c = hist[b];
    roff[b] = starts[b];
    gbase[b] = c ? (u32)atomicAdd(&bptr[b], (int)c) : 0u;
  }
  __syncthreads();
  // pass 2: rank into bucket-grouped LDS staging
  for (int j = tid; j < tot; j += 256) {
    int e = base + j;
    u32 r = (u32)rows[e];
    u32 b = r >> NB_SH;
    u32 p = atomicAdd(&roff[b], 1u);
    s_col[p] = (u32)cols[e] | ((r & ((1u << NB_SH) - 1u)) << 17);
    s_val[p] = (u16)f32_to_bf16_rne(vals[e]);
    s_bkt[p] = (u16)b;
  }
  __syncthreads();
  // flush: consecutive LDS records -> consecutive global slots within runs
  for (int i = tid; i < tot; i += 256) {
    u32 b = s_bkt[i];
    u32 d = gbase[b] + ((u32)i - starts[b]);
    bcol[d] = s_col[i];
    bval[d] = s_val[i];
  }
}

// One WG per 128-node bucket; fp32 accumulators in LDS (64 KB), ds_add_f32
// atomics. Edges unordered within bucket (order-free accumulate). 8 gathers in
// flight per wave to cover L2/L3 latency at 2 WG/CU occupancy.
__global__ __launch_bounds__(256) void agg_bucket(const int* __restrict__ bhist,
                                                  const int* __restrict__ bbase,
                                                  const u32* __restrict__ bcol,
                                                  const u16* __restrict__ bval,
                                                  const u32* __restrict__ h,
                                                  float* __restrict__ out, int N) {
  __shared__ floatx4 accv[AGG_NB * DIM / 4];  // 64 KB
  float* acc = (float*)accv;
  int tid = threadIdx.x;
  int b = blockIdx.x;
  floatx4 zv = {0.f, 0.f, 0.f, 0.f};
  for (int i = tid; i < AGG_NB * DIM / 4; i += 256) accv[i] = zv;
  __syncthreads();

  int lane = tid & 63, wave = tid >> 6;
  int base = bbase[b];
  int T = bhist[b];
  int end = base + T;
  int nch = T >> 5;  // chunks of 32 edges (8 per wave)
  for (int i = 0; i < nch; ++i) {
    int e = base + i * 32 + wave * 8;
    u32 cw[8];
    float v[8];
    u32 d[8];
#pragma unroll
    for (int k = 0; k < 8; ++k) cw[k] = bcol[e + k];
#pragma unroll
    for (int k = 0; k < 8; ++k) v[k] = bf16_to_f32(bval[e + k]);
#pragma unroll
    for (int k = 0; k < 8; ++k) d[k] = h[(size_t)(cw[k] & 0x1FFFFu) * DIM2 + lane];
#pragma unroll
    for (int k = 0; k < 8; ++k) {
      float* ap = &acc[(cw[k] >> 17) * DIM + 2 * lane];
      atomicAdd(ap, v[k] * bf16_to_f32(d[k] & 0xffffu));
      atomicAdd(ap + 1, v[k] * bf16_to_f32(d[k] >> 16));
    }
  }
  for (int e = base + nch * 32 + wave; e < end; e += 4) {
    u32 cw = bcol[e];
    float v = bf16_to_f32(bval[e]);
    u32 d = h[(size_t)(cw & 0x1FFFFu) * DIM2 + lane];
    float* ap = &acc[(cw >> 17) * DIM + 2 * lane];
    atomicAdd(ap, v * bf16_to_f32(d & 0xffffu));
    atomicAdd(ap + 1, v * bf16_to_f32(d >> 16));
  }
  __syncthreads();

  int nodeBase = b << NB_SH;
  for (int i = tid; i < AGG_NB * DIM / 4; i += 256) {
    int r = i >> 5;  // DIM/4 = 32 float4 per row
    int node = nodeBase + r;
    if (node < N) {
      floatx4 a = accv[i];
      floatx4 o = {fmaxf(a.x, 0.f), fmaxf(a.y, 0.f), fmaxf(a.z, 0.f), fmaxf(a.w, 0.f)};
      *(floatx4*)(out + (size_t)node * DIM + (i & 31) * 4) = o;
    }
  }
}

extern "C" void kernel_launch(void* const* d_in, const int* in_sizes, int n_in,
                              void* d_out, int out_size, void* d_ws, size_t ws_size,
                              hipStream_t stream) {
  const float* x    = (const float*)d_in[0];  // fp32 [N,128]
  const int*   rows = (const int*)d_in[1];    // int32 [E]
  const int*   cols = (const int*)d_in[2];    // int32 [E]
  const float* vals = (const float*)d_in[3];  // fp32 [E]
  const float* W    = (const float*)d_in[4];  // fp32 [128,128]

  const int N = in_sizes[0] / DIM;  // 100000
  const int E = in_sizes[1];        // 3200000
  const int B = (N + AGG_NB - 1) / AGG_NB;  // 782 buckets

  char* wsb = (char*)d_ws;
  size_t o = 0;
  u16* h = (u16*)wsb;                    o += (size_t)N * DIM * sizeof(u16);  // 25.6 MB
  int* bhist = (int*)(wsb + o);          o += (size_t)NBK * 4;
  int* bbase = (int*)(wsb + o);          o += (size_t)NBK * 4;
  int* bptr  = (int*)(wsb + o);          o += (size_t)NBK * 4;
  u32* bcol  = (u32*)(wsb + o);          o += (size_t)E * 4;                  // 12.8 MB
  u16* bval  = (u16*)(wsb + o);          o += (size_t)E * 2;                  // 6.4 MB

  const int nsc = (E + SC_C - 1) / SC_C;  // 782

  zero_kernel<<<(NBK + 255) / 256, 256, 0, stream>>>(bhist, NBK);
  gemm_mfma<<<(N + 63) / 64, 256, 0, stream>>>(x, W, h, N);
  bucket_hist<<<nsc, 256, 0, stream>>>(rows, bhist, E, B);
  bucket_scan<<<1, 256, 0, stream>>>(bhist, bbase, bptr);
  bin_scatter<<<nsc, 256, 0, stream>>>(rows, cols, vals, bptr, bcol, bval, E);
  agg_bucket<<<B, 256, 0, stream>>>(bhist, bbase, bcol, bval, (const u32*)h,
                                    (float*)d_out, N);
}

// Round 2
// 447.119 us; speedup vs baseline: 6.4582x; 6.4582x over previous
//
#include <hip/hip_runtime.h>
#include <stdint.h>

typedef unsigned short u16;
typedef unsigned int u32;
typedef __attribute__((ext_vector_type(8))) short short8;
typedef __attribute__((ext_vector_type(4))) float floatx4;

#define DIM 128
#define DIM2 64   // h dwords per row (2 bf16 per dword)
#define NBK 2048  // scan width (max buckets); B = ceil(N/64) = 1563 for N=100000
#define NB_SH 6   // 64 nodes per bucket
#define AGG_NB 64
#define AGG_C 2048  // edge records per agg sort-chunk
#define SC_C 4096   // edges per scatter/hist workgroup chunk

__device__ __forceinline__ u32 f32_to_bf16_rne(float f) {
  u32 u = __float_as_uint(f);
  u32 r = u + 0x7fffu + ((u >> 16) & 1u);
  return r >> 16;
}
__device__ __forceinline__ float bf16_to_f32(u32 u) { return __uint_as_float(u << 16); }
__device__ __forceinline__ u32 pack2bf16(float a, float b) {
  return f32_to_bf16_rne(a) | (f32_to_bf16_rne(b) << 16);
}

union FragU {
  u32 d[4];
  short8 s;
};

// h = x @ W^T via bf16 MFMA (unchanged; frag maps verified m89/m120).
__global__ __launch_bounds__(256) void gemm_mfma(const float* __restrict__ x,
                                                 const float* __restrict__ W,
                                                 u16* __restrict__ h, int N) {
  __shared__ u32 Wl[DIM * DIM2];  // 32 KB
  int tid = threadIdx.x;
#pragma unroll
  for (int i = 0; i < 8; ++i) {
    int ga = tid + 256 * i;
    int o = ga >> 4, g = ga & 15;
    const float* src = W + (size_t)o * DIM + g * 8;
    floatx4 f0 = *(const floatx4*)src;
    floatx4 f1 = *(const floatx4*)(src + 4);
    int slot = (g + o) & 15;
    u32* dst = &Wl[o * DIM2 + slot * 4];
    dst[0] = pack2bf16(f0.x, f0.y);
    dst[1] = pack2bf16(f0.z, f0.w);
    dst[2] = pack2bf16(f1.x, f1.y);
    dst[3] = pack2bf16(f1.z, f1.w);
  }
  __syncthreads();

  int lane = tid & 63;
  int wave = tid >> 6;
  int nodeBase = (blockIdx.x * 4 + wave) * 16;
  if (nodeBase >= N) return;
  int m = lane & 15;
  int kg = lane >> 4;

  short8 a[4];
  const float* xr = x + (size_t)(nodeBase + m) * DIM + kg * 8;
#pragma unroll
  for (int kt = 0; kt < 4; ++kt) {
    floatx4 f0 = *(const floatx4*)(xr + kt * 32);
    floatx4 f1 = *(const floatx4*)(xr + kt * 32 + 4);
    FragU fu;
    fu.d[0] = pack2bf16(f0.x, f0.y);
    fu.d[1] = pack2bf16(f0.z, f0.w);
    fu.d[2] = pack2bf16(f1.x, f1.y);
    fu.d[3] = pack2bf16(f1.z, f1.w);
    a[kt] = fu.s;
  }

#pragma unroll
  for (int ot = 0; ot < 8; ++ot) {
    int o = ot * 16 + m;
    floatx4 acc = {0.f, 0.f, 0.f, 0.f};
#pragma unroll
    for (int kt = 0; kt < 4; ++kt) {
      int slot = (kt * 4 + kg + o) & 15;
      short8 b = *(short8*)&Wl[o * DIM2 + slot * 4];
      acc = __builtin_amdgcn_mfma_f32_16x16x32_bf16(a[kt], b, acc, 0, 0, 0);
    }
#pragma unroll
    for (int r = 0; r < 4; ++r) {
      int node = nodeBase + kg * 4 + r;
      h[(size_t)node * DIM + ot * 16 + m] = (u16)f32_to_bf16_rne(acc[r]);
    }
  }
}

__global__ void zero_kernel(int* __restrict__ p, int n) {
  int i = blockIdx.x * blockDim.x + threadIdx.x;
  if (i < n) p[i] = 0;
}

// Exclusive scan over 2048 LDS counters with 256 threads (8 contiguous each).
__device__ __forceinline__ void scan2048(u32* cnt, u32* excl, u32* wtot) {
  int tid = threadIdx.x, lane = tid & 63, wave = tid >> 6;
  u32 c[8], sum = 0;
#pragma unroll
  for (int k = 0; k < 8; ++k) {
    c[k] = cnt[tid * 8 + k];
    sum += c[k];
  }
  u32 inc = sum;
#pragma unroll
  for (int d = 1; d < 64; d <<= 1) {
    u32 t = __shfl_up(inc, d, 64);
    if (lane >= d) inc += t;
  }
  if (lane == 63) wtot[wave] = inc;
  __syncthreads();
  u32 wbase = 0;
  for (int w = 0; w < wave; ++w) wbase += wtot[w];
  u32 run = wbase + inc - sum;
#pragma unroll
  for (int k = 0; k < 8; ++k) {
    excl[tid * 8 + k] = run;
    run += c[k];
  }
  __syncthreads();
}

// Global bucket histogram: LDS pre-aggregation, one global atomic per (WG,bucket).
__global__ __launch_bounds__(256) void bucket_hist(const int* __restrict__ rows,
                                                   int* __restrict__ bhist, int E, int B) {
  __shared__ u32 hist[NBK];
  int tid = threadIdx.x;
  for (int b = tid; b < NBK; b += 256) hist[b] = 0;
  __syncthreads();
  int base = blockIdx.x * SC_C;
  for (int j = tid; j < SC_C; j += 256) {
    int e = base + j;
    if (e < E) atomicAdd(&hist[((u32)rows[e]) >> NB_SH], 1u);
  }
  __syncthreads();
  for (int b = tid; b < B; b += 256) {
    u32 c = hist[b];
    if (c) atomicAdd(&bhist[b], (int)c);
  }
}

// One-WG exclusive scan of bucket counts -> bbase (agg reads) and bptr (scatter bumps).
__global__ __launch_bounds__(256) void bucket_scan(const int* __restrict__ bhist,
                                                   int* __restrict__ bbase,
                                                   int* __restrict__ bptr) {
  __shared__ u32 cnt[NBK], excl[NBK], wtot[4];
  int tid = threadIdx.x;
  for (int b = tid; b < NBK; b += 256) cnt[b] = (u32)bhist[b];
  __syncthreads();
  scan2048(cnt, excl, wtot);
  for (int b = tid; b < NBK; b += 256) {
    bbase[b] = (int)excl[b];
    bptr[b] = (int)excl[b];
  }
}

// LDS-binned scatter: stage 4096 records grouped by bucket in LDS, flush as
// near-coalesced runs. (Replaced the 15x write-amplified per-node scatter.)
__global__ __launch_bounds__(256) void bin_scatter(const int* __restrict__ rows,
                                                   const int* __restrict__ cols,
                                                   const float* __restrict__ vals,
                                                   int* __restrict__ bptr,
                                                   u32* __restrict__ bcol,
                                                   u16* __restrict__ bval, int E) {
  __shared__ u32 hist[NBK], starts[NBK], roff[NBK], gbase[NBK], wtot[4];
  __shared__ u32 s_col[SC_C];
  __shared__ u16 s_val[SC_C];
  __shared__ u16 s_bkt[SC_C];
  int tid = threadIdx.x;
  int base = blockIdx.x * SC_C;
  int tot = min(SC_C, E - base);

  for (int b = tid; b < NBK; b += 256) hist[b] = 0;
  __syncthreads();
  // pass 1: local histogram (int LDS atomics)
  for (int j = tid; j < tot; j += 256) {
    atomicAdd(&hist[((u32)rows[base + j]) >> NB_SH], 1u);
  }
  __syncthreads();
  scan2048(hist, starts, wtot);
  // reserve global space per bucket; init running offsets
  for (int b = tid; b < NBK; b += 256) {
    u32 c = hist[b];
    roff[b] = starts[b];
    gbase[b] = c ? (u32)atomicAdd(&bptr[b], (int)c) : 0u;
  }
  __syncthreads();
  // pass 2: rank into bucket-grouped LDS staging
  for (int j = tid; j < tot; j += 256) {
    int e = base + j;
    u32 r = (u32)rows[e];
    u32 b = r >> NB_SH;
    u32 p = atomicAdd(&roff[b], 1u);
    s_col[p] = (u32)cols[e] | ((r & ((1u << NB_SH) - 1u)) << 17);
    s_val[p] = (u16)f32_to_bf16_rne(vals[e]);
    s_bkt[p] = (u16)b;
  }
  __syncthreads();
  // flush: consecutive LDS records -> consecutive global slots within runs
  for (int i = tid; i < tot; i += 256) {
    u32 b = s_bkt[i];
    u32 d = gbase[b] + ((u32)i - starts[b]);
    bcol[d] = s_col[i];
    bval[d] = s_val[i];
  }
}

// One WG per 64-node bucket. Per 2048-record chunk: LDS counting-sort by node
// (int atomics on 64 counters only), then wave w walks runs of its own 16 nodes
// accumulating in REGISTERS (no fp atomics anywhere); one plain LDS RMW per
// node per chunk (race-free: fixed wave<->node ownership). R1's per-edge fp32
// LDS atomicAdd (2666 us, 512 cyc/edge serialization) is gone.
__global__ __launch_bounds__(256) void agg_bucket(const int* __restrict__ bhist,
                                                  const int* __restrict__ bbase,
                                                  const u32* __restrict__ bcol,
                                                  const u16* __restrict__ bval,
                                                  const u32* __restrict__ h,
                                                  float* __restrict__ out, int N) {
  __shared__ floatx4 accv[AGG_NB * DIM / 4];  // 32 KB
  __shared__ u32 s_col[AGG_C];                // 8 KB
  __shared__ u16 s_val[AGG_C];                // 4 KB
  __shared__ u32 cnt[AGG_NB], excl[AGG_NB], ptr[AGG_NB];
  float* acc = (float*)accv;
  int tid = threadIdx.x, lane = tid & 63, wave = tid >> 6;
  int b = blockIdx.x;
  floatx4 zv = {0.f, 0.f, 0.f, 0.f};
  for (int i = tid; i < AGG_NB * DIM / 4; i += 256) accv[i] = zv;

  int base = bbase[b], T = bhist[b];

  for (int c0 = 0; c0 < T; c0 += AGG_C) {
    int n = min(AGG_C, T - c0);
    if (tid < AGG_NB) cnt[tid] = 0;
    __syncthreads();
    // pass A: load chunk into registers + node histogram
    u32 rc[8], rb[8];
#pragma unroll
    for (int k = 0; k < 8; ++k) {
      rc[k] = 0;
      rb[k] = 0;
      int j = tid + 256 * k;
      if (j < n) {
        rc[k] = bcol[base + c0 + j];
        rb[k] = bval[base + c0 + j];
        atomicAdd(&cnt[rc[k] >> 17], 1u);
      }
    }
    __syncthreads();
    // scan 64 counters (wave 0)
    if (tid < 64) {
      u32 c = cnt[tid];
      u32 inc = c;
#pragma unroll
      for (int d = 1; d < 64; d <<= 1) {
        u32 t = __shfl_up(inc, d, 64);
        if (lane >= d) inc += t;
      }
      excl[tid] = inc - c;
      ptr[tid] = inc - c;
    }
    __syncthreads();
    // pass B: rank into node-sorted LDS staging
#pragma unroll
    for (int k = 0; k < 8; ++k) {
      int j = tid + 256 * k;
      if (j < n) {
        u32 p = atomicAdd(&ptr[rc[k] >> 17], 1u);
        s_col[p] = rc[k] & 0x1FFFFu;
        s_val[p] = (u16)rb[k];
      }
    }
    __syncthreads();
    // pass C: wave w processes nodes [w*16, w*16+16): register accumulate
    int nb0 = wave * 16;
    for (int nn = 0; nn < 16; ++nn) {
      int node = nb0 + nn;
      int e0 = excl[node];
      int e1 = (int)ptr[node];  // == excl + count after pass B
      if (e1 <= e0) continue;
      float a0 = 0.f, a1 = 0.f;
      int e = e0;
      for (; e + 4 <= e1; e += 4) {
        u32 c0_ = s_col[e], c1_ = s_col[e + 1], c2_ = s_col[e + 2], c3_ = s_col[e + 3];
        float v0 = bf16_to_f32(s_val[e]);
        float v1 = bf16_to_f32(s_val[e + 1]);
        float v2 = bf16_to_f32(s_val[e + 2]);
        float v3 = bf16_to_f32(s_val[e + 3]);
        u32 d0 = h[(size_t)c0_ * DIM2 + lane];
        u32 d1 = h[(size_t)c1_ * DIM2 + lane];
        u32 d2 = h[(size_t)c2_ * DIM2 + lane];
        u32 d3 = h[(size_t)c3_ * DIM2 + lane];
        a0 += v0 * bf16_to_f32(d0 & 0xffffu);
        a1 += v0 * bf16_to_f32(d0 >> 16);
        a0 += v1 * bf16_to_f32(d1 & 0xffffu);
        a1 += v1 * bf16_to_f32(d1 >> 16);
        a0 += v2 * bf16_to_f32(d2 & 0xffffu);
        a1 += v2 * bf16_to_f32(d2 >> 16);
        a0 += v3 * bf16_to_f32(d3 & 0xffffu);
        a1 += v3 * bf16_to_f32(d3 >> 16);
      }
      for (; e < e1; ++e) {
        u32 cw = s_col[e];
        float v = bf16_to_f32(s_val[e]);
        u32 d = h[(size_t)cw * DIM2 + lane];
        a0 += v * bf16_to_f32(d & 0xffffu);
        a1 += v * bf16_to_f32(d >> 16);
      }
      float* ap = &acc[node * DIM + 2 * lane];
      ap[0] += a0;  // plain LDS RMW; only wave w ever touches node rows w*16..
      ap[1] += a1;
    }
    __syncthreads();  // staging/counters reused by next chunk
  }

  int nodeBase = b * AGG_NB;
  for (int i = tid; i < AGG_NB * DIM / 4; i += 256) {
    int r = i >> 5;  // 32 float4 per row
    int node = nodeBase + r;
    if (node < N) {
      floatx4 a = accv[i];
      floatx4 o = {fmaxf(a.x, 0.f), fmaxf(a.y, 0.f), fmaxf(a.z, 0.f), fmaxf(a.w, 0.f)};
      *(floatx4*)(out + (size_t)node * DIM + (i & 31) * 4) = o;
    }
  }
}

extern "C" void kernel_launch(void* const* d_in, const int* in_sizes, int n_in,
                              void* d_out, int out_size, void* d_ws, size_t ws_size,
                              hipStream_t stream) {
  const float* x    = (const float*)d_in[0];  // fp32 [N,128]
  const int*   rows = (const int*)d_in[1];    // int32 [E]
  const int*   cols = (const int*)d_in[2];    // int32 [E]
  const float* vals = (const float*)d_in[3];  // fp32 [E]
  const float* W    = (const float*)d_in[4];  // fp32 [128,128]

  const int N = in_sizes[0] / DIM;  // 100000
  const int E = in_sizes[1];        // 3200000
  const int B = (N + AGG_NB - 1) / AGG_NB;  // 1563 buckets

  char* wsb = (char*)d_ws;
  size_t o = 0;
  u16* h = (u16*)wsb;                    o += (size_t)N * DIM * sizeof(u16);  // 25.6 MB
  int* bhist = (int*)(wsb + o);          o += (size_t)NBK * 4;
  int* bbase = (int*)(wsb + o);          o += (size_t)NBK * 4;
  int* bptr  = (int*)(wsb + o);          o += (size_t)NBK * 4;
  u32* bcol  = (u32*)(wsb + o);          o += (size_t)E * 4;                  // 12.8 MB
  u16* bval  = (u16*)(wsb + o);          o += (size_t)E * 2;                  // 6.4 MB

  const int nsc = (E + SC_C - 1) / SC_C;  // 782

  zero_kernel<<<(NBK + 255) / 256, 256, 0, stream>>>(bhist, NBK);
  gemm_mfma<<<(N + 63) / 64, 256, 0, stream>>>(x, W, h, N);
  bucket_hist<<<nsc, 256, 0, stream>>>(rows, bhist, E, B);
  bucket_scan<<<1, 256, 0, stream>>>(bhist, bbase, bptr);
  bin_scatter<<<nsc, 256, 0, stream>>>(rows, cols, vals, bptr, bcol, bval, E);
  agg_bucket<<<B, 256, 0, stream>>>(bhist, bbase, bcol, bval, (const u32*)h,
                                    (float*)d_out, N);
}

// Round 3
// 399.982 us; speedup vs baseline: 7.2193x; 1.1178x over previous
//
#include <hip/hip_runtime.h>
#include <stdint.h>

typedef unsigned short u16;
typedef unsigned int u32;
typedef __attribute__((ext_vector_type(8))) short short8;
typedef __attribute__((ext_vector_type(4))) float floatx4;

#define DIM 128
#define DIM2 64   // h dwords per row (2 bf16 per dword)
#define NBK 2048  // scan width (max buckets); B = ceil(N/64) = 1563 for N=100000
#define NB_SH 6   // 64 nodes per bucket
#define AGG_NB 64
#define AGG_C 1024  // edge records per agg sort-chunk (staging 6 KB -> 4 WG/CU)
#define SC_C 4096   // edges per scatter/hist workgroup chunk

__device__ __forceinline__ u32 f32_to_bf16_rne(float f) {
  u32 u = __float_as_uint(f);
  u32 r = u + 0x7fffu + ((u >> 16) & 1u);
  return r >> 16;
}
__device__ __forceinline__ float bf16_to_f32(u32 u) { return __uint_as_float(u << 16); }
__device__ __forceinline__ u32 pack2bf16(float a, float b) {
  return f32_to_bf16_rne(a) | (f32_to_bf16_rne(b) << 16);
}

union FragU {
  u32 d[4];
  short8 s;
};

// h = x @ W^T via bf16 MFMA (unchanged; frag maps verified m89/m120).
__global__ __launch_bounds__(256) void gemm_mfma(const float* __restrict__ x,
                                                 const float* __restrict__ W,
                                                 u16* __restrict__ h, int N) {
  __shared__ u32 Wl[DIM * DIM2];  // 32 KB
  int tid = threadIdx.x;
#pragma unroll
  for (int i = 0; i < 8; ++i) {
    int ga = tid + 256 * i;
    int o = ga >> 4, g = ga & 15;
    const float* src = W + (size_t)o * DIM + g * 8;
    floatx4 f0 = *(const floatx4*)src;
    floatx4 f1 = *(const floatx4*)(src + 4);
    int slot = (g + o) & 15;
    u32* dst = &Wl[o * DIM2 + slot * 4];
    dst[0] = pack2bf16(f0.x, f0.y);
    dst[1] = pack2bf16(f0.z, f0.w);
    dst[2] = pack2bf16(f1.x, f1.y);
    dst[3] = pack2bf16(f1.z, f1.w);
  }
  __syncthreads();

  int lane = tid & 63;
  int wave = tid >> 6;
  int nodeBase = (blockIdx.x * 4 + wave) * 16;
  if (nodeBase >= N) return;
  int m = lane & 15;
  int kg = lane >> 4;

  short8 a[4];
  const float* xr = x + (size_t)(nodeBase + m) * DIM + kg * 8;
#pragma unroll
  for (int kt = 0; kt < 4; ++kt) {
    floatx4 f0 = *(const floatx4*)(xr + kt * 32);
    floatx4 f1 = *(const floatx4*)(xr + kt * 32 + 4);
    FragU fu;
    fu.d[0] = pack2bf16(f0.x, f0.y);
    fu.d[1] = pack2bf16(f0.z, f0.w);
    fu.d[2] = pack2bf16(f1.x, f1.y);
    fu.d[3] = pack2bf16(f1.z, f1.w);
    a[kt] = fu.s;
  }

#pragma unroll
  for (int ot = 0; ot < 8; ++ot) {
    int o = ot * 16 + m;
    floatx4 acc = {0.f, 0.f, 0.f, 0.f};
#pragma unroll
    for (int kt = 0; kt < 4; ++kt) {
      int slot = (kt * 4 + kg + o) & 15;
      short8 b = *(short8*)&Wl[o * DIM2 + slot * 4];
      acc = __builtin_amdgcn_mfma_f32_16x16x32_bf16(a[kt], b, acc, 0, 0, 0);
    }
#pragma unroll
    for (int r = 0; r < 4; ++r) {
      int node = nodeBase + kg * 4 + r;
      h[(size_t)node * DIM + ot * 16 + m] = (u16)f32_to_bf16_rne(acc[r]);
    }
  }
}

__global__ void zero_kernel(int* __restrict__ p, int n) {
  int i = blockIdx.x * blockDim.x + threadIdx.x;
  if (i < n) p[i] = 0;
}

// Exclusive scan over 2048 LDS counters with 256 threads (8 contiguous each).
__device__ __forceinline__ void scan2048(u32* cnt, u32* excl, u32* wtot) {
  int tid = threadIdx.x, lane = tid & 63, wave = tid >> 6;
  u32 c[8], sum = 0;
#pragma unroll
  for (int k = 0; k < 8; ++k) {
    c[k] = cnt[tid * 8 + k];
    sum += c[k];
  }
  u32 inc = sum;
#pragma unroll
  for (int d = 1; d < 64; d <<= 1) {
    u32 t = __shfl_up(inc, d, 64);
    if (lane >= d) inc += t;
  }
  if (lane == 63) wtot[wave] = inc;
  __syncthreads();
  u32 wbase = 0;
  for (int w = 0; w < wave; ++w) wbase += wtot[w];
  u32 run = wbase + inc - sum;
#pragma unroll
  for (int k = 0; k < 8; ++k) {
    excl[tid * 8 + k] = run;
    run += c[k];
  }
  __syncthreads();
}

// Global bucket histogram: LDS pre-aggregation, one global atomic per (WG,bucket).
__global__ __launch_bounds__(256) void bucket_hist(const int* __restrict__ rows,
                                                   int* __restrict__ bhist, int E, int B) {
  __shared__ u32 hist[NBK];
  int tid = threadIdx.x;
  for (int b = tid; b < NBK; b += 256) hist[b] = 0;
  __syncthreads();
  int base = blockIdx.x * SC_C;
  for (int j = tid; j < SC_C; j += 256) {
    int e = base + j;
    if (e < E) atomicAdd(&hist[((u32)rows[e]) >> NB_SH], 1u);
  }
  __syncthreads();
  for (int b = tid; b < B; b += 256) {
    u32 c = hist[b];
    if (c) atomicAdd(&bhist[b], (int)c);
  }
}

// One-WG exclusive scan of bucket counts -> bbase (agg reads) and bptr (scatter bumps).
__global__ __launch_bounds__(256) void bucket_scan(const int* __restrict__ bhist,
                                                   int* __restrict__ bbase,
                                                   int* __restrict__ bptr) {
  __shared__ u32 cnt[NBK], excl[NBK], wtot[4];
  int tid = threadIdx.x;
  for (int b = tid; b < NBK; b += 256) cnt[b] = (u32)bhist[b];
  __syncthreads();
  scan2048(cnt, excl, wtot);
  for (int b = tid; b < NBK; b += 256) {
    bbase[b] = (int)excl[b];
    bptr[b] = (int)excl[b];
  }
}

// LDS-binned scatter: stage 4096 records grouped by bucket in LDS, flush as
// near-coalesced runs. (Replaced the 15x write-amplified per-node scatter.)
__global__ __launch_bounds__(256) void bin_scatter(const int* __restrict__ rows,
                                                   const int* __restrict__ cols,
                                                   const float* __restrict__ vals,
                                                   int* __restrict__ bptr,
                                                   u32* __restrict__ bcol,
                                                   u16* __restrict__ bval, int E) {
  __shared__ u32 hist[NBK], starts[NBK], roff[NBK], gbase[NBK], wtot[4];
  __shared__ u32 s_col[SC_C];
  __shared__ u16 s_val[SC_C];
  __shared__ u16 s_bkt[SC_C];
  int tid = threadIdx.x;
  int base = blockIdx.x * SC_C;
  int tot = min(SC_C, E - base);

  for (int b = tid; b < NBK; b += 256) hist[b] = 0;
  __syncthreads();
  // pass 1: local histogram (int LDS atomics)
  for (int j = tid; j < tot; j += 256) {
    atomicAdd(&hist[((u32)rows[base + j]) >> NB_SH], 1u);
  }
  __syncthreads();
  scan2048(hist, starts, wtot);
  // reserve global space per bucket; init running offsets
  for (int b = tid; b < NBK; b += 256) {
    u32 c = hist[b];
    roff[b] = starts[b];
    gbase[b] = c ? (u32)atomicAdd(&bptr[b], (int)c) : 0u;
  }
  __syncthreads();
  // pass 2: rank into bucket-grouped LDS staging
  for (int j = tid; j < tot; j += 256) {
    int e = base + j;
    u32 r = (u32)rows[e];
    u32 b = r >> NB_SH;
    u32 p = atomicAdd(&roff[b], 1u);
    s_col[p] = (u32)cols[e] | ((r & ((1u << NB_SH) - 1u)) << 17);
    s_val[p] = (u16)f32_to_bf16_rne(vals[e]);
    s_bkt[p] = (u16)b;
  }
  __syncthreads();
  // flush: consecutive LDS records -> consecutive global slots within runs
  for (int i = tid; i < tot; i += 256) {
    u32 b = s_bkt[i];
    u32 d = gbase[b] + ((u32)i - starts[b]);
    bcol[d] = s_col[i];
    bval[d] = s_val[i];
  }
}

// One WG per 64-node bucket. Per 1024-record chunk: LDS counting-sort by node
// (int atomics on 64 counters), then wave w walks its 16 nodes' edges as ONE
// CONTIGUOUS segment with a 16-deep gather pipeline (R2 exposed ~1 full gather
// latency per 4-edge group + per-run tails -> 40 cyc/edge/CU, 75% stall).
// Register accumulate per run; flush to LDS acc on node change (scalar branch
// via readfirstlane on the wave-uniform node id). No fp atomics anywhere.
__global__ __launch_bounds__(256) void agg_bucket(const int* __restrict__ bhist,
                                                  const int* __restrict__ bbase,
                                                  const u32* __restrict__ bcol,
                                                  const u16* __restrict__ bval,
                                                  const u32* __restrict__ h,
                                                  float* __restrict__ out, int N) {
  __shared__ floatx4 accv[AGG_NB * DIM / 4];  // 32 KB
  __shared__ u32 s_col[AGG_C];                // 4 KB
  __shared__ u16 s_val[AGG_C];                // 2 KB
  __shared__ u32 cnt[AGG_NB], excl[AGG_NB], ptr[AGG_NB];
  float* acc = (float*)accv;
  int tid = threadIdx.x, lane = tid & 63, wave = tid >> 6;
  int b = blockIdx.x;
  floatx4 zv = {0.f, 0.f, 0.f, 0.f};
  for (int i = tid; i < AGG_NB * DIM / 4; i += 256) accv[i] = zv;

  int base = bbase[b], T = bhist[b];

  float a0 = 0.f, a1 = 0.f;
  int curn = -1;  // persists across chunks (runs may span chunk boundary)

  for (int c0 = 0; c0 < T; c0 += AGG_C) {
    int n = min(AGG_C, T - c0);
    if (tid < AGG_NB) cnt[tid] = 0;
    __syncthreads();
    // pass A: load chunk into registers + node histogram
    u32 rc[4], rb[4];
#pragma unroll
    for (int k = 0; k < 4; ++k) {
      rc[k] = 0;
      rb[k] = 0;
      int j = tid + 256 * k;
      if (j < n) {
        rc[k] = bcol[base + c0 + j];
        rb[k] = bval[base + c0 + j];
        atomicAdd(&cnt[rc[k] >> 17], 1u);
      }
    }
    __syncthreads();
    // scan 64 counters (wave 0)
    if (tid < 64) {
      u32 c = cnt[tid];
      u32 inc = c;
#pragma unroll
      for (int d = 1; d < 64; d <<= 1) {
        u32 t = __shfl_up(inc, d, 64);
        if (lane >= d) inc += t;
      }
      excl[tid] = inc - c;
      ptr[tid] = inc - c;
    }
    __syncthreads();
    // pass B: rank into node-sorted LDS staging
#pragma unroll
    for (int k = 0; k < 4; ++k) {
      int j = tid + 256 * k;
      if (j < n) {
        u32 p = atomicAdd(&ptr[rc[k] >> 17], 1u);
        s_col[p] = rc[k];
        s_val[p] = (u16)rb[k];
      }
    }
    __syncthreads();
    // pass C: wave w's 16 nodes are contiguous [excl[w*16], ptr[w*16+15]).
    // Flat walk, 16 gathers in flight, run-flush on node change.
    int wbeg = (int)excl[wave * 16];
    int wend = (int)ptr[wave * 16 + 15];
    for (int e = wbeg; e < wend; e += 16) {
      u32 mt[16];
      float vv[16];
#pragma unroll
      for (int g = 0; g < 16; ++g) {
        int ee = e + g;
        bool act = ee < wend;
        int idx = act ? ee : (wend - 1);  // valid slot; v=0 neutralizes
        mt[g] = s_col[idx];
        vv[g] = act ? bf16_to_f32(s_val[idx]) : 0.f;
      }
      u32 hd[16];
#pragma unroll
      for (int g = 0; g < 16; ++g) {
        hd[g] = h[(size_t)(mt[g] & 0x1FFFFu) * DIM2 + lane];
      }
#pragma unroll
      for (int g = 0; g < 16; ++g) {
        int nid = __builtin_amdgcn_readfirstlane((int)(mt[g] >> 17));
        if (nid != curn) {  // scalar branch, once per run
          if (curn >= 0) {
            float2* ap = (float2*)&acc[curn * DIM + 2 * lane];
            float2 t = *ap;
            t.x += a0;
            t.y += a1;
            *ap = t;
          }
          curn = nid;
          a0 = 0.f;
          a1 = 0.f;
        }
        float v = vv[g];
        a0 += v * bf16_to_f32(hd[g] & 0xffffu);
        a1 += v * bf16_to_f32(hd[g] >> 16);
      }
    }
  }
  // final flush
  if (curn >= 0) {
    float2* ap = (float2*)&acc[curn * DIM + 2 * lane];
    float2 t = *ap;
    t.x += a0;
    t.y += a1;
    *ap = t;
  }
  __syncthreads();

  int nodeBase = b * AGG_NB;
  for (int i = tid; i < AGG_NB * DIM / 4; i += 256) {
    int r = i >> 5;  // 32 float4 per row
    int node = nodeBase + r;
    if (node < N) {
      floatx4 a = accv[i];
      floatx4 o = {fmaxf(a.x, 0.f), fmaxf(a.y, 0.f), fmaxf(a.z, 0.f), fmaxf(a.w, 0.f)};
      *(floatx4*)(out + (size_t)node * DIM + (i & 31) * 4) = o;
    }
  }
}

extern "C" void kernel_launch(void* const* d_in, const int* in_sizes, int n_in,
                              void* d_out, int out_size, void* d_ws, size_t ws_size,
                              hipStream_t stream) {
  const float* x    = (const float*)d_in[0];  // fp32 [N,128]
  const int*   rows = (const int*)d_in[1];    // int32 [E]
  const int*   cols = (const int*)d_in[2];    // int32 [E]
  const float* vals = (const float*)d_in[3];  // fp32 [E]
  const float* W    = (const float*)d_in[4];  // fp32 [128,128]

  const int N = in_sizes[0] / DIM;  // 100000
  const int E = in_sizes[1];        // 3200000
  const int B = (N + AGG_NB - 1) / AGG_NB;  // 1563 buckets

  char* wsb = (char*)d_ws;
  size_t o = 0;
  u16* h = (u16*)wsb;                    o += (size_t)N * DIM * sizeof(u16);  // 25.6 MB
  int* bhist = (int*)(wsb + o);          o += (size_t)NBK * 4;
  int* bbase = (int*)(wsb + o);          o += (size_t)NBK * 4;
  int* bptr  = (int*)(wsb + o);          o += (size_t)NBK * 4;
  u32* bcol  = (u32*)(wsb + o);          o += (size_t)E * 4;                  // 12.8 MB
  u16* bval  = (u16*)(wsb + o);          o += (size_t)E * 2;                  // 6.4 MB

  const int nsc = (E + SC_C - 1) / SC_C;  // 782

  zero_kernel<<<(NBK + 255) / 256, 256, 0, stream>>>(bhist, NBK);
  gemm_mfma<<<(N + 63) / 64, 256, 0, stream>>>(x, W, h, N);
  bucket_hist<<<nsc, 256, 0, stream>>>(rows, bhist, E, B);
  bucket_scan<<<1, 256, 0, stream>>>(bhist, bbase, bptr);
  bin_scatter<<<nsc, 256, 0, stream>>>(rows, cols, vals, bptr, bcol, bval, E);
  agg_bucket<<<B, 256, 0, stream>>>(bhist, bbase, bcol, bval, (const u32*)h,
                                    (float*)d_out, N);
}

// Round 4
// 361.865 us; speedup vs baseline: 7.9798x; 1.1053x over previous
//
#include <hip/hip_runtime.h>
#include <stdint.h>

typedef unsigned short u16;
typedef unsigned int u32;
typedef unsigned long long u64;
typedef __attribute__((ext_vector_type(8))) short short8;
typedef __attribute__((ext_vector_type(4))) float floatx4;

#define DIM 128
#define DIM2 64     // h dwords per row (2 bf16 per dword)
#define NBK 2048    // scan width (max buckets); B = ceil(N/64) = 1563
#define NB_SH 6     // 64 nodes per bucket
#define AGG_NB 64
#define AGG_CAP 2560  // max staged records/bucket (mean 2048, std 45 -> +11 sigma)
#define SC_C 4096     // edges per scatter/hist workgroup chunk

__device__ __forceinline__ u32 f32_to_bf16_rne(float f) {
  u32 u = __float_as_uint(f);
  u32 r = u + 0x7fffu + ((u >> 16) & 1u);
  return r >> 16;
}
__device__ __forceinline__ float bf16_to_f32(u32 u) { return __uint_as_float(u << 16); }
__device__ __forceinline__ u32 pack2bf16(float a, float b) {
  return f32_to_bf16_rne(a) | (f32_to_bf16_rne(b) << 16);
}

union FragU {
  u32 d[4];
  short8 s;
};

// h = x @ W^T via bf16 MFMA (unchanged; frag maps verified m89/m120).
__global__ __launch_bounds__(256) void gemm_mfma(const float* __restrict__ x,
                                                 const float* __restrict__ W,
                                                 u16* __restrict__ h, int N) {
  __shared__ u32 Wl[DIM * DIM2];  // 32 KB
  int tid = threadIdx.x;
#pragma unroll
  for (int i = 0; i < 8; ++i) {
    int ga = tid + 256 * i;
    int o = ga >> 4, g = ga & 15;
    const float* src = W + (size_t)o * DIM + g * 8;
    floatx4 f0 = *(const floatx4*)src;
    floatx4 f1 = *(const floatx4*)(src + 4);
    int slot = (g + o) & 15;
    u32* dst = &Wl[o * DIM2 + slot * 4];
    dst[0] = pack2bf16(f0.x, f0.y);
    dst[1] = pack2bf16(f0.z, f0.w);
    dst[2] = pack2bf16(f1.x, f1.y);
    dst[3] = pack2bf16(f1.z, f1.w);
  }
  __syncthreads();

  int lane = tid & 63;
  int wave = tid >> 6;
  int nodeBase = (blockIdx.x * 4 + wave) * 16;
  if (nodeBase >= N) return;
  int m = lane & 15;
  int kg = lane >> 4;

  short8 a[4];
  const float* xr = x + (size_t)(nodeBase + m) * DIM + kg * 8;
#pragma unroll
  for (int kt = 0; kt < 4; ++kt) {
    floatx4 f0 = *(const floatx4*)(xr + kt * 32);
    floatx4 f1 = *(const floatx4*)(xr + kt * 32 + 4);
    FragU fu;
    fu.d[0] = pack2bf16(f0.x, f0.y);
    fu.d[1] = pack2bf16(f0.z, f0.w);
    fu.d[2] = pack2bf16(f1.x, f1.y);
    fu.d[3] = pack2bf16(f1.z, f1.w);
    a[kt] = fu.s;
  }

#pragma unroll
  for (int ot = 0; ot < 8; ++ot) {
    int o = ot * 16 + m;
    floatx4 acc = {0.f, 0.f, 0.f, 0.f};
#pragma unroll
    for (int kt = 0; kt < 4; ++kt) {
      int slot = (kt * 4 + kg + o) & 15;
      short8 b = *(short8*)&Wl[o * DIM2 + slot * 4];
      acc = __builtin_amdgcn_mfma_f32_16x16x32_bf16(a[kt], b, acc, 0, 0, 0);
    }
#pragma unroll
    for (int r = 0; r < 4; ++r) {
      int node = nodeBase + kg * 4 + r;
      h[(size_t)node * DIM + ot * 16 + m] = (u16)f32_to_bf16_rne(acc[r]);
    }
  }
}

__global__ void zero_kernel(int* __restrict__ p, int n) {
  int i = blockIdx.x * blockDim.x + threadIdx.x;
  if (i < n) p[i] = 0;
}

// Exclusive scan over 2048 LDS counters with 256 threads (8 contiguous each).
__device__ __forceinline__ void scan2048(u32* cnt, u32* excl, u32* wtot) {
  int tid = threadIdx.x, lane = tid & 63, wave = tid >> 6;
  u32 c[8], sum = 0;
#pragma unroll
  for (int k = 0; k < 8; ++k) {
    c[k] = cnt[tid * 8 + k];
    sum += c[k];
  }
  u32 inc = sum;
#pragma unroll
  for (int d = 1; d < 64; d <<= 1) {
    u32 t = __shfl_up(inc, d, 64);
    if (lane >= d) inc += t;
  }
  if (lane == 63) wtot[wave] = inc;
  __syncthreads();
  u32 wbase = 0;
  for (int w = 0; w < wave; ++w) wbase += wtot[w];
  u32 run = wbase + inc - sum;
#pragma unroll
  for (int k = 0; k < 8; ++k) {
    excl[tid * 8 + k] = run;
    run += c[k];
  }
  __syncthreads();
}

// Global bucket histogram: LDS pre-aggregation, one global atomic per (WG,bucket).
__global__ __launch_bounds__(256) void bucket_hist(const int* __restrict__ rows,
                                                   int* __restrict__ bhist, int E, int B) {
  __shared__ u32 hist[NBK];
  int tid = threadIdx.x;
  for (int b = tid; b < NBK; b += 256) hist[b] = 0;
  __syncthreads();
  int base = blockIdx.x * SC_C;
  for (int j = tid; j < SC_C; j += 256) {
    int e = base + j;
    if (e < E) atomicAdd(&hist[((u32)rows[e]) >> NB_SH], 1u);
  }
  __syncthreads();
  for (int b = tid; b < B; b += 256) {
    u32 c = hist[b];
    if (c) atomicAdd(&bhist[b], (int)c);
  }
}

// One-WG exclusive scan of bucket counts -> bbase (agg reads) and bptr (scatter bumps).
__global__ __launch_bounds__(256) void bucket_scan(const int* __restrict__ bhist,
                                                   int* __restrict__ bbase,
                                                   int* __restrict__ bptr) {
  __shared__ u32 cnt[NBK], excl[NBK], wtot[4];
  int tid = threadIdx.x;
  for (int b = tid; b < NBK; b += 256) cnt[b] = (u32)bhist[b];
  __syncthreads();
  scan2048(cnt, excl, wtot);
  for (int b = tid; b < NBK; b += 256) {
    bbase[b] = (int)excl[b];
    bptr[b] = (int)excl[b];
  }
}

// LDS-binned scatter. Record lo-word pre-encodes what agg needs:
//   lo = (node_local<<26) | (col<<8)   (col<<8 IS the h-row byte offset)
//   val stored as bf16 in bval.
__global__ __launch_bounds__(256) void bin_scatter(const int* __restrict__ rows,
                                                   const int* __restrict__ cols,
                                                   const float* __restrict__ vals,
                                                   int* __restrict__ bptr,
                                                   u32* __restrict__ bcol,
                                                   u16* __restrict__ bval, int E) {
  __shared__ u32 hist[NBK];  // counts, then reused as running offsets
  __shared__ u32 starts[NBK];
  __shared__ u32 gbase[NBK];
  __shared__ u32 wtot[4];
  __shared__ u32 s_lo[SC_C];
  __shared__ u16 s_val[SC_C];
  __shared__ u16 s_bkt[SC_C];
  int tid = threadIdx.x;
  int base = blockIdx.x * SC_C;
  int tot = min(SC_C, E - base);

  for (int b = tid; b < NBK; b += 256) hist[b] = 0;
  __syncthreads();
  // pass 1: local histogram (int LDS atomics)
  for (int j = tid; j < tot; j += 256) {
    atomicAdd(&hist[((u32)rows[base + j]) >> NB_SH], 1u);
  }
  __syncthreads();
  scan2048(hist, starts, wtot);
  // reserve global space per bucket; reuse hist as running offsets
  for (int b = tid; b < NBK; b += 256) {
    u32 c = hist[b];
    gbase[b] = c ? (u32)atomicAdd(&bptr[b], (int)c) : 0u;
    hist[b] = starts[b];
  }
  __syncthreads();
  // pass 2: rank into bucket-grouped LDS staging
  for (int j = tid; j < tot; j += 256) {
    int e = base + j;
    u32 r = (u32)rows[e];
    u32 bk = r >> NB_SH;
    u32 p = atomicAdd(&hist[bk], 1u);
    s_lo[p] = ((r & 63u) << 26) | ((u32)cols[e] << 8);
    s_val[p] = (u16)f32_to_bf16_rne(vals[e]);
    s_bkt[p] = (u16)bk;
  }
  __syncthreads();
  // flush: consecutive LDS records -> consecutive global slots within runs
  for (int i = tid; i < tot; i += 256) {
    u32 bk = s_bkt[i];
    u32 d = gbase[bk] + ((u32)i - starts[bk]);
    bcol[d] = s_lo[i];
    bval[d] = s_val[i];
  }
}

// One WG per 64-node bucket. Whole bucket staged+sorted in LDS (CAP=2560,
// +11 sigma over mean 2048 -> overflow path never taken for this input), then
// each wave flat-walks its 16 nodes' contiguous segment with a depth-8 gather
// pipeline and flushes each completed node row DIRECTLY to global (relu'd,
// coalesced 512B). No LDS accumulator: LDS 40->21 KB (7 WG/CU). Record u64 in
// LDS: hi = f32 bits of val (no unpack), lo = (nlocal<<26)|(col<<8) so gather
// offset is one v_and + v_add against an SGPR base.
__global__ __launch_bounds__(256) void agg_bucket(const int* __restrict__ bhist,
                                                  const int* __restrict__ bbase,
                                                  const u32* __restrict__ bcol,
                                                  const u16* __restrict__ bval,
                                                  const u32* __restrict__ h,
                                                  float* __restrict__ out, int N) {
  __shared__ u64 s_rec[AGG_CAP];  // 20 KB
  __shared__ u32 cnt[AGG_NB], excl[AGG_NB], ptr[AGG_NB];
  int tid = threadIdx.x, lane = tid & 63, wave = tid >> 6;
  int b = blockIdx.x;
  int base = bbase[b], T = bhist[b];
  int nodeBase = b << NB_SH;
  int lane4 = lane * 4;
  const char* hb = (const char*)h;

  if (T <= AGG_CAP) {
    if (tid < AGG_NB) cnt[tid] = 0;
    __syncthreads();
    // pass A: load bucket into registers + node histogram
    u32 rlo[10], rv[10];
#pragma unroll
    for (int k = 0; k < 10; ++k) {
      int j = tid + 256 * k;
      rlo[k] = 0;
      rv[k] = 0;
      if (j < T) {
        rlo[k] = bcol[base + j];
        rv[k] = bval[base + j];
        atomicAdd(&cnt[rlo[k] >> 26], 1u);
      }
    }
    __syncthreads();
    if (tid < 64) {
      u32 c = cnt[tid], inc = c;
#pragma unroll
      for (int d = 1; d < 64; d <<= 1) {
        u32 t = __shfl_up(inc, d, 64);
        if (lane >= d) inc += t;
      }
      excl[tid] = inc - c;
      ptr[tid] = inc - c;
    }
    __syncthreads();
    // pass B: rank into node-sorted LDS staging (u64 records)
#pragma unroll
    for (int k = 0; k < 10; ++k) {
      int j = tid + 256 * k;
      if (j < T) {
        u32 p = atomicAdd(&ptr[rlo[k] >> 26], 1u);
        s_rec[p] = ((u64)(rv[k] << 16) << 32) | rlo[k];
      }
    }
    __syncthreads();
    // pass C: flat walk of my wave's contiguous segment, depth-8 pipeline
    int wbeg = (int)excl[wave * 16];
    int wend = (int)ptr[wave * 16 + 15];
    float a0 = 0.f, a1 = 0.f;
    int curn = -1;
    for (int e = wbeg; e < wend; e += 8) {
      u32 lo8[8];
      float v8[8];
      u32 hd[8];
#pragma unroll
      for (int g = 0; g < 8; ++g) {
        int ee = e + g;
        bool act = ee < wend;
        u64 r = s_rec[act ? ee : (wend - 1)];  // wave-uniform broadcast read
        lo8[g] = (u32)r;
        v8[g] = act ? __uint_as_float((u32)(r >> 32)) : 0.f;
      }
#pragma unroll
      for (int g = 0; g < 8; ++g) {
        hd[g] = *(const u32*)(hb + ((lo8[g] & 0x01FFFF00u) + lane4));
      }
#pragma unroll
      for (int g = 0; g < 8; ++g) {
        int nid = __builtin_amdgcn_readfirstlane((int)(lo8[g] >> 26));
        if (nid != curn) {  // scalar branch, once per run
          if (curn >= 0) {
            float2 o = make_float2(fmaxf(a0, 0.f), fmaxf(a1, 0.f));
            *(float2*)(out + (size_t)(nodeBase + curn) * DIM + 2 * lane) = o;
          }
          curn = nid;
          a0 = 0.f;
          a1 = 0.f;
        }
        float v = v8[g];
        a0 += v * bf16_to_f32(hd[g] & 0xffffu);
        a1 += v * bf16_to_f32(hd[g] >> 16);
      }
    }
    if (curn >= 0) {
      float2 o = make_float2(fmaxf(a0, 0.f), fmaxf(a1, 0.f));
      *(float2*)(out + (size_t)(nodeBase + curn) * DIM + 2 * lane) = o;
    }
    // epilogue: zero rows for nodes with no edges
    for (int nn = 0; nn < 16; ++nn) {
      int nl = wave * 16 + nn;
      int node = nodeBase + nl;
      if (cnt[nl] == 0 && node < N) {
        *(float2*)(out + (size_t)node * DIM + 2 * lane) = make_float2(0.f, 0.f);
      }
    }
  } else {
    // Guaranteed-correct fallback (statistically unreachable for this input):
    // per-node full scan of the bucket's edge list.
    for (int nn = 0; nn < 16; ++nn) {
      int nl = wave * 16 + nn;
      int node = nodeBase + nl;
      if (node >= N) continue;
      float a0 = 0.f, a1 = 0.f;
      for (int e = 0; e < T; ++e) {
        u32 lo = bcol[base + e];
        if ((int)(lo >> 26) == nl) {
          u32 d = *(const u32*)(hb + ((lo & 0x01FFFF00u) + lane4));
          float v = bf16_to_f32(bval[base + e]);
          a0 += v * bf16_to_f32(d & 0xffffu);
          a1 += v * bf16_to_f32(d >> 16);
        }
      }
      *(float2*)(out + (size_t)node * DIM + 2 * lane) =
          make_float2(fmaxf(a0, 0.f), fmaxf(a1, 0.f));
    }
  }
}

extern "C" void kernel_launch(void* const* d_in, const int* in_sizes, int n_in,
                              void* d_out, int out_size, void* d_ws, size_t ws_size,
                              hipStream_t stream) {
  const float* x    = (const float*)d_in[0];  // fp32 [N,128]
  const int*   rows = (const int*)d_in[1];    // int32 [E]
  const int*   cols = (const int*)d_in[2];    // int32 [E]
  const float* vals = (const float*)d_in[3];  // fp32 [E]
  const float* W    = (const float*)d_in[4];  // fp32 [128,128]

  const int N = in_sizes[0] / DIM;  // 100000
  const int E = in_sizes[1];        // 3200000
  const int B = (N + AGG_NB - 1) / AGG_NB;  // 1563 buckets

  char* wsb = (char*)d_ws;
  size_t o = 0;
  u16* h = (u16*)wsb;                    o += (size_t)N * DIM * sizeof(u16);  // 25.6 MB
  int* bhist = (int*)(wsb + o);          o += (size_t)NBK * 4;
  int* bbase = (int*)(wsb + o);          o += (size_t)NBK * 4;
  int* bptr  = (int*)(wsb + o);          o += (size_t)NBK * 4;
  u32* bcol  = (u32*)(wsb + o);          o += (size_t)E * 4;                  // 12.8 MB
  u16* bval  = (u16*)(wsb + o);          o += (size_t)E * 2;                  // 6.4 MB

  const int nsc = (E + SC_C - 1) / SC_C;  // 782

  zero_kernel<<<(NBK + 255) / 256, 256, 0, stream>>>(bhist, NBK);
  gemm_mfma<<<(N + 63) / 64, 256, 0, stream>>>(x, W, h, N);
  bucket_hist<<<nsc, 256, 0, stream>>>(rows, bhist, E, B);
  bucket_scan<<<1, 256, 0, stream>>>(bhist, bbase, bptr);
  bin_scatter<<<nsc, 256, 0, stream>>>(rows, cols, vals, bptr, bcol, bval, E);
  agg_bucket<<<B, 256, 0, stream>>>(bhist, bbase, bcol, bval, (const u32*)h,
                                    (float*)d_out, N);
}

// Round 5
// 344.865 us; speedup vs baseline: 8.3731x; 1.0493x over previous
//
#include <hip/hip_runtime.h>
#include <stdint.h>

typedef unsigned short u16;
typedef unsigned int u32;
typedef unsigned long long u64;
typedef __attribute__((ext_vector_type(8))) short short8;
typedef __attribute__((ext_vector_type(4))) float floatx4;

#define DIM 128
#define DIM2 64     // h dwords per row (2 bf16 per dword)
#define NBK 2048    // scan width (max buckets); B = ceil(N/64) = 1563
#define NB_SH 6     // 64 nodes per bucket
#define AGG_NB 64
#define AGG_CAP 2560  // max staged records/bucket (mean 2048, std 45 -> +11 sigma)
#define SC_C 8192     // edges per scatter chunk (runs ~5.2/bucket -> half the segments)
#define HIST_C 4096   // edges per hist workgroup chunk

__device__ __forceinline__ u32 f32_to_bf16_rne(float f) {
  u32 u = __float_as_uint(f);
  u32 r = u + 0x7fffu + ((u >> 16) & 1u);
  return r >> 16;
}
__device__ __forceinline__ float bf16_to_f32(u32 u) { return __uint_as_float(u << 16); }
__device__ __forceinline__ u32 pack2bf16(float a, float b) {
  return f32_to_bf16_rne(a) | (f32_to_bf16_rne(b) << 16);
}

union FragU {
  u32 d[4];
  short8 s;
};

// h = x @ W^T via bf16 MFMA. Grid-stride over 64-node tiles with exactly 256
// WGs (1/CU): removes the 391-WG 1.53x imbalance and stages W once per CU.
__global__ __launch_bounds__(256) void gemm_mfma(const float* __restrict__ x,
                                                 const float* __restrict__ W,
                                                 u16* __restrict__ h, int N) {
  __shared__ u32 Wl[DIM * DIM2];  // 32 KB
  int tid = threadIdx.x;
#pragma unroll
  for (int i = 0; i < 8; ++i) {
    int ga = tid + 256 * i;
    int o = ga >> 4, g = ga & 15;
    const float* src = W + (size_t)o * DIM + g * 8;
    floatx4 f0 = *(const floatx4*)src;
    floatx4 f1 = *(const floatx4*)(src + 4);
    int slot = (g + o) & 15;
    u32* dst = &Wl[o * DIM2 + slot * 4];
    dst[0] = pack2bf16(f0.x, f0.y);
    dst[1] = pack2bf16(f0.z, f0.w);
    dst[2] = pack2bf16(f1.x, f1.y);
    dst[3] = pack2bf16(f1.z, f1.w);
  }
  __syncthreads();

  int lane = tid & 63;
  int wave = tid >> 6;
  int m = lane & 15;
  int kg = lane >> 4;
  int ntile = (N + 63) >> 6;  // 64-node tiles

  for (int t = blockIdx.x; t < ntile; t += 256) {
    int nodeBase = t * 64 + wave * 16;
    if (nodeBase >= N) continue;

    short8 a[4];
    const float* xr = x + (size_t)(nodeBase + m) * DIM + kg * 8;
#pragma unroll
    for (int kt = 0; kt < 4; ++kt) {
      floatx4 f0 = *(const floatx4*)(xr + kt * 32);
      floatx4 f1 = *(const floatx4*)(xr + kt * 32 + 4);
      FragU fu;
      fu.d[0] = pack2bf16(f0.x, f0.y);
      fu.d[1] = pack2bf16(f0.z, f0.w);
      fu.d[2] = pack2bf16(f1.x, f1.y);
      fu.d[3] = pack2bf16(f1.z, f1.w);
      a[kt] = fu.s;
    }

#pragma unroll
    for (int ot = 0; ot < 8; ++ot) {
      int o = ot * 16 + m;
      floatx4 acc = {0.f, 0.f, 0.f, 0.f};
#pragma unroll
      for (int kt = 0; kt < 4; ++kt) {
        int slot = (kt * 4 + kg + o) & 15;
        short8 b = *(short8*)&Wl[o * DIM2 + slot * 4];
        acc = __builtin_amdgcn_mfma_f32_16x16x32_bf16(a[kt], b, acc, 0, 0, 0);
      }
#pragma unroll
      for (int r = 0; r < 4; ++r) {
        int node = nodeBase + kg * 4 + r;
        h[(size_t)node * DIM + ot * 16 + m] = (u16)f32_to_bf16_rne(acc[r]);
      }
    }
  }
}

__global__ void zero_kernel(int* __restrict__ p, int n) {
  int i = blockIdx.x * blockDim.x + threadIdx.x;
  if (i < n) p[i] = 0;
}

// Exclusive scan over 2048 LDS counters with 256 threads (8 contiguous each).
__device__ __forceinline__ void scan2048(u32* cnt, u32* excl, u32* wtot) {
  int tid = threadIdx.x, lane = tid & 63, wave = tid >> 6;
  u32 c[8], sum = 0;
#pragma unroll
  for (int k = 0; k < 8; ++k) {
    c[k] = cnt[tid * 8 + k];
    sum += c[k];
  }
  u32 inc = sum;
#pragma unroll
  for (int d = 1; d < 64; d <<= 1) {
    u32 t = __shfl_up(inc, d, 64);
    if (lane >= d) inc += t;
  }
  if (lane == 63) wtot[wave] = inc;
  __syncthreads();
  u32 wbase = 0;
  for (int w = 0; w < wave; ++w) wbase += wtot[w];
  u32 run = wbase + inc - sum;
#pragma unroll
  for (int k = 0; k < 8; ++k) {
    excl[tid * 8 + k] = run;
    run += c[k];
  }
  __syncthreads();
}

// Global bucket histogram: LDS pre-aggregation, one global atomic per (WG,bucket).
__global__ __launch_bounds__(256) void bucket_hist(const int* __restrict__ rows,
                                                   int* __restrict__ bhist, int E, int B) {
  __shared__ u32 hist[NBK];
  int tid = threadIdx.x;
  for (int b = tid; b < NBK; b += 256) hist[b] = 0;
  __syncthreads();
  int base = blockIdx.x * HIST_C;
  for (int j = tid; j < HIST_C; j += 256) {
    int e = base + j;
    if (e < E) atomicAdd(&hist[((u32)rows[e]) >> NB_SH], 1u);
  }
  __syncthreads();
  for (int b = tid; b < B; b += 256) {
    u32 c = hist[b];
    if (c) atomicAdd(&bhist[b], (int)c);
  }
}

// One-WG exclusive scan of bucket counts -> bbase (agg reads) and bptr (scatter bumps).
__global__ __launch_bounds__(256) void bucket_scan(const int* __restrict__ bhist,
                                                   int* __restrict__ bbase,
                                                   int* __restrict__ bptr) {
  __shared__ u32 cnt[NBK], excl[NBK], wtot[4];
  int tid = threadIdx.x;
  for (int b = tid; b < NBK; b += 256) cnt[b] = (u32)bhist[b];
  __syncthreads();
  scan2048(cnt, excl, wtot);
  for (int b = tid; b < NBK; b += 256) {
    bbase[b] = (int)excl[b];
    bptr[b] = (int)excl[b];
  }
}

// LDS-binned scatter v2 (perm-based). Stages ONE packed u32 per edge:
//   rec = (bk<<19) | (nlocal<<13) | j   (bk<2048, nlocal<64, j<8192)
// Flush walks bucket-sorted order, re-gathers cols/vals from the L2-hot 32KB
// chunk window, and writes records as ~5.2-long coalescable runs. Output
// encoding for agg: lo = (nlocal<<26)|(col<<8), val = bf16.
__global__ __launch_bounds__(256) void bin_scatter(const int* __restrict__ rows,
                                                   const int* __restrict__ cols,
                                                   const float* __restrict__ vals,
                                                   int* __restrict__ bptr,
                                                   u32* __restrict__ bcol,
                                                   u16* __restrict__ bval, int E) {
  __shared__ u32 hist[NBK];  // counts, then running offsets
  __shared__ u32 starts[NBK];
  __shared__ u32 gbase[NBK];
  __shared__ u32 wtot[4];
  __shared__ u32 s_rec[SC_C];  // 32 KB
  int tid = threadIdx.x;
  int base = blockIdx.x * SC_C;
  int tot = min(SC_C, E - base);

  for (int b = tid; b < NBK; b += 256) hist[b] = 0;
  __syncthreads();
  // pass 1: local histogram
  for (int j = tid; j < tot; j += 256) {
    atomicAdd(&hist[((u32)rows[base + j]) >> NB_SH], 1u);
  }
  __syncthreads();
  scan2048(hist, starts, wtot);
  // reserve global space per bucket; reuse hist as running offsets
  for (int b = tid; b < NBK; b += 256) {
    u32 c = hist[b];
    gbase[b] = c ? (u32)atomicAdd(&bptr[b], (int)c) : 0u;
    hist[b] = starts[b];
  }
  __syncthreads();
  // pass 2: rank packed perm records into bucket-grouped LDS
  for (int j = tid; j < tot; j += 256) {
    u32 r = (u32)rows[base + j];
    u32 bk = r >> NB_SH;
    u32 p = atomicAdd(&hist[bk], 1u);
    s_rec[p] = (bk << 19) | ((r & 63u) << 13) | (u32)j;
  }
  __syncthreads();
  // flush: bucket-sorted order -> near-coalesced global runs
  for (int i = tid; i < tot; i += 256) {
    u32 rec = s_rec[i];
    u32 bk = rec >> 19;
    u32 nl = (rec >> 13) & 63u;
    int e = base + (int)(rec & 8191u);
    u32 d = gbase[bk] + ((u32)i - starts[bk]);
    bcol[d] = (nl << 26) | ((u32)cols[e] << 8);
    bval[d] = (u16)f32_to_bf16_rne(vals[e]);
  }
}

// One WG per 64-node bucket (unchanged from R4: whole bucket staged+sorted in
// LDS, flat walk with depth-8 gather pipeline, direct relu'd global flush).
__global__ __launch_bounds__(256) void agg_bucket(const int* __restrict__ bhist,
                                                  const int* __restrict__ bbase,
                                                  const u32* __restrict__ bcol,
                                                  const u16* __restrict__ bval,
                                                  const u32* __restrict__ h,
                                                  float* __restrict__ out, int N) {
  __shared__ u64 s_rec[AGG_CAP];  // 20 KB
  __shared__ u32 cnt[AGG_NB], excl[AGG_NB], ptr[AGG_NB];
  int tid = threadIdx.x, lane = tid & 63, wave = tid >> 6;
  int b = blockIdx.x;
  int base = bbase[b], T = bhist[b];
  int nodeBase = b << NB_SH;
  int lane4 = lane * 4;
  const char* hb = (const char*)h;

  if (T <= AGG_CAP) {
    if (tid < AGG_NB) cnt[tid] = 0;
    __syncthreads();
    // pass A: load bucket into registers + node histogram
    u32 rlo[10], rv[10];
#pragma unroll
    for (int k = 0; k < 10; ++k) {
      int j = tid + 256 * k;
      rlo[k] = 0;
      rv[k] = 0;
      if (j < T) {
        rlo[k] = bcol[base + j];
        rv[k] = bval[base + j];
        atomicAdd(&cnt[rlo[k] >> 26], 1u);
      }
    }
    __syncthreads();
    if (tid < 64) {
      u32 c = cnt[tid], inc = c;
#pragma unroll
      for (int d = 1; d < 64; d <<= 1) {
        u32 t = __shfl_up(inc, d, 64);
        if (lane >= d) inc += t;
      }
      excl[tid] = inc - c;
      ptr[tid] = inc - c;
    }
    __syncthreads();
    // pass B: rank into node-sorted LDS staging (u64 records)
#pragma unroll
    for (int k = 0; k < 10; ++k) {
      int j = tid + 256 * k;
      if (j < T) {
        u32 p = atomicAdd(&ptr[rlo[k] >> 26], 1u);
        s_rec[p] = ((u64)(rv[k] << 16) << 32) | rlo[k];
      }
    }
    __syncthreads();
    // pass C: flat walk of my wave's contiguous segment, depth-8 pipeline
    int wbeg = (int)excl[wave * 16];
    int wend = (int)ptr[wave * 16 + 15];
    float a0 = 0.f, a1 = 0.f;
    int curn = -1;
    for (int e = wbeg; e < wend; e += 8) {
      u32 lo8[8];
      float v8[8];
      u32 hd[8];
#pragma unroll
      for (int g = 0; g < 8; ++g) {
        int ee = e + g;
        bool act = ee < wend;
        u64 r = s_rec[act ? ee : (wend - 1)];  // wave-uniform broadcast read
        lo8[g] = (u32)r;
        v8[g] = act ? __uint_as_float((u32)(r >> 32)) : 0.f;
      }
#pragma unroll
      for (int g = 0; g < 8; ++g) {
        hd[g] = *(const u32*)(hb + ((lo8[g] & 0x01FFFF00u) + lane4));
      }
#pragma unroll
      for (int g = 0; g < 8; ++g) {
        int nid = __builtin_amdgcn_readfirstlane((int)(lo8[g] >> 26));
        if (nid != curn) {  // scalar branch, once per run
          if (curn >= 0) {
            float2 o = make_float2(fmaxf(a0, 0.f), fmaxf(a1, 0.f));
            *(float2*)(out + (size_t)(nodeBase + curn) * DIM + 2 * lane) = o;
          }
          curn = nid;
          a0 = 0.f;
          a1 = 0.f;
        }
        float v = v8[g];
        a0 += v * bf16_to_f32(hd[g] & 0xffffu);
        a1 += v * bf16_to_f32(hd[g] >> 16);
      }
    }
    if (curn >= 0) {
      float2 o = make_float2(fmaxf(a0, 0.f), fmaxf(a1, 0.f));
      *(float2*)(out + (size_t)(nodeBase + curn) * DIM + 2 * lane) = o;
    }
    // epilogue: zero rows for nodes with no edges
    for (int nn = 0; nn < 16; ++nn) {
      int nl = wave * 16 + nn;
      int node = nodeBase + nl;
      if (cnt[nl] == 0 && node < N) {
        *(float2*)(out + (size_t)node * DIM + 2 * lane) = make_float2(0.f, 0.f);
      }
    }
  } else {
    // Guaranteed-correct fallback (statistically unreachable for this input):
    // per-node full scan of the bucket's edge list.
    for (int nn = 0; nn < 16; ++nn) {
      int nl = wave * 16 + nn;
      int node = nodeBase + nl;
      if (node >= N) continue;
      float a0 = 0.f, a1 = 0.f;
      for (int e = 0; e < T; ++e) {
        u32 lo = bcol[base + e];
        if ((int)(lo >> 26) == nl) {
          u32 d = *(const u32*)(hb + ((lo & 0x01FFFF00u) + lane4));
          float v = bf16_to_f32(bval[base + e]);
          a0 += v * bf16_to_f32(d & 0xffffu);
          a1 += v * bf16_to_f32(d >> 16);
        }
      }
      *(float2*)(out + (size_t)node * DIM + 2 * lane) =
          make_float2(fmaxf(a0, 0.f), fmaxf(a1, 0.f));
    }
  }
}

extern "C" void kernel_launch(void* const* d_in, const int* in_sizes, int n_in,
                              void* d_out, int out_size, void* d_ws, size_t ws_size,
                              hipStream_t stream) {
  const float* x    = (const float*)d_in[0];  // fp32 [N,128]
  const int*   rows = (const int*)d_in[1];    // int32 [E]
  const int*   cols = (const int*)d_in[2];    // int32 [E]
  const float* vals = (const float*)d_in[3];  // fp32 [E]
  const float* W    = (const float*)d_in[4];  // fp32 [128,128]

  const int N = in_sizes[0] / DIM;  // 100000
  const int E = in_sizes[1];        // 3200000
  const int B = (N + AGG_NB - 1) / AGG_NB;  // 1563 buckets

  char* wsb = (char*)d_ws;
  size_t o = 0;
  u16* h = (u16*)wsb;                    o += (size_t)N * DIM * sizeof(u16);  // 25.6 MB
  int* bhist = (int*)(wsb + o);          o += (size_t)NBK * 4;
  int* bbase = (int*)(wsb + o);          o += (size_t)NBK * 4;
  int* bptr  = (int*)(wsb + o);          o += (size_t)NBK * 4;
  u32* bcol  = (u32*)(wsb + o);          o += (size_t)E * 4;                  // 12.8 MB
  u16* bval  = (u16*)(wsb + o);          o += (size_t)E * 2;                  // 6.4 MB

  const int nhist = (E + HIST_C - 1) / HIST_C;  // 782
  const int nsc = (E + SC_C - 1) / SC_C;        // 391

  zero_kernel<<<(NBK + 255) / 256, 256, 0, stream>>>(bhist, NBK);
  gemm_mfma<<<256, 256, 0, stream>>>(x, W, h, N);
  bucket_hist<<<nhist, 256, 0, stream>>>(rows, bhist, E, B);
  bucket_scan<<<1, 256, 0, stream>>>(bhist, bbase, bptr);
  bin_scatter<<<nsc, 256, 0, stream>>>(rows, cols, vals, bptr, bcol, bval, E);
  agg_bucket<<<B, 256, 0, stream>>>(bhist, bbase, bcol, bval, (const u32*)h,
                                    (float*)d_out, N);
}

// Round 6
// 342.728 us; speedup vs baseline: 8.4254x; 1.0062x over previous
//
#include <hip/hip_runtime.h>
#include <stdint.h>

typedef unsigned short u16;
typedef unsigned int u32;
typedef unsigned long long u64;
typedef __attribute__((ext_vector_type(8))) short short8;
typedef __attribute__((ext_vector_type(4))) float floatx4;

#define DIM 128
#define DIM2 64     // h dwords per row (2 bf16 per dword)
#define NBK 1792    // scatter scan width >= B = ceil(N/64) = 1563
#define NBK_PT 7    // NBK / 256
#define NB_SH 6     // 64 nodes per bucket
#define AGG_NB 64
#define AGG_CAP 2560  // max staged records/bucket (mean 2048, std 45 -> +11 sigma)
#define SC_C 8192     // edges per scatter chunk / region size

__device__ __forceinline__ u32 f32_to_bf16_rne(float f) {
  u32 u = __float_as_uint(f);
  u32 r = u + 0x7fffu + ((u >> 16) & 1u);
  return r >> 16;
}
__device__ __forceinline__ float bf16_to_f32(u32 u) { return __uint_as_float(u << 16); }
__device__ __forceinline__ u32 pack2bf16(float a, float b) {
  return f32_to_bf16_rne(a) | (f32_to_bf16_rne(b) << 16);
}

union FragU {
  u32 d[4];
  short8 s;
};

// h = x @ W^T via bf16 MFMA. Grid-stride over 64-node tiles with exactly 256
// WGs (1/CU); W staged once per CU.
__global__ __launch_bounds__(256) void gemm_mfma(const float* __restrict__ x,
                                                 const float* __restrict__ W,
                                                 u16* __restrict__ h, int N) {
  __shared__ u32 Wl[DIM * DIM2];  // 32 KB
  int tid = threadIdx.x;
#pragma unroll
  for (int i = 0; i < 8; ++i) {
    int ga = tid + 256 * i;
    int o = ga >> 4, g = ga & 15;
    const float* src = W + (size_t)o * DIM + g * 8;
    floatx4 f0 = *(const floatx4*)src;
    floatx4 f1 = *(const floatx4*)(src + 4);
    int slot = (g + o) & 15;
    u32* dst = &Wl[o * DIM2 + slot * 4];
    dst[0] = pack2bf16(f0.x, f0.y);
    dst[1] = pack2bf16(f0.z, f0.w);
    dst[2] = pack2bf16(f1.x, f1.y);
    dst[3] = pack2bf16(f1.z, f1.w);
  }
  __syncthreads();

  int lane = tid & 63;
  int wave = tid >> 6;
  int m = lane & 15;
  int kg = lane >> 4;
  int ntile = (N + 63) >> 6;  // 64-node tiles

  for (int t = blockIdx.x; t < ntile; t += 256) {
    int nodeBase = t * 64 + wave * 16;
    if (nodeBase >= N) continue;

    short8 a[4];
    const float* xr = x + (size_t)(nodeBase + m) * DIM + kg * 8;
#pragma unroll
    for (int kt = 0; kt < 4; ++kt) {
      floatx4 f0 = *(const floatx4*)(xr + kt * 32);
      floatx4 f1 = *(const floatx4*)(xr + kt * 32 + 4);
      FragU fu;
      fu.d[0] = pack2bf16(f0.x, f0.y);
      fu.d[1] = pack2bf16(f0.z, f0.w);
      fu.d[2] = pack2bf16(f1.x, f1.y);
      fu.d[3] = pack2bf16(f1.z, f1.w);
      a[kt] = fu.s;
    }

#pragma unroll
    for (int ot = 0; ot < 8; ++ot) {
      int o = ot * 16 + m;
      floatx4 acc = {0.f, 0.f, 0.f, 0.f};
#pragma unroll
      for (int kt = 0; kt < 4; ++kt) {
        int slot = (kt * 4 + kg + o) & 15;
        short8 b = *(short8*)&Wl[o * DIM2 + slot * 4];
        acc = __builtin_amdgcn_mfma_f32_16x16x32_bf16(a[kt], b, acc, 0, 0, 0);
      }
#pragma unroll
      for (int r = 0; r < 4; ++r) {
        int node = nodeBase + kg * 4 + r;
        h[(size_t)node * DIM + ot * 16 + m] = (u16)f32_to_bf16_rne(acc[r]);
      }
    }
  }
}

// Exclusive scan over NBK=1792 LDS counters, 7 contiguous per thread.
__device__ __forceinline__ void scan_nbk(u32* cnt, u32* excl, u32* wtot) {
  int tid = threadIdx.x, lane = tid & 63, wave = tid >> 6;
  u32 c[NBK_PT], sum = 0;
#pragma unroll
  for (int k = 0; k < NBK_PT; ++k) {
    c[k] = cnt[tid * NBK_PT + k];
    sum += c[k];
  }
  u32 inc = sum;
#pragma unroll
  for (int d = 1; d < 64; d <<= 1) {
    u32 t = __shfl_up(inc, d, 64);
    if (lane >= d) inc += t;
  }
  if (lane == 63) wtot[wave] = inc;
  __syncthreads();
  u32 wbase = 0;
  for (int w = 0; w < wave; ++w) wbase += wtot[w];
  u32 run = wbase + inc - sum;
#pragma unroll
  for (int k = 0; k < NBK_PT; ++k) {
    excl[tid * NBK_PT + k] = run;
    run += c[k];
  }
  __syncthreads();
}

// Region-local sort-scatter: NO global atomics, NO hist/scan kernels.
// Each WG bucket-sorts its 8192-edge chunk in LDS and streams it to its OWN
// region bcol/bval[wg*8192 ..] (perfectly coalesced), plus a directory row
// dir[wg][b] = (start<<16)|cnt so agg can find its segments.
__global__ __launch_bounds__(256) void sort_scatter(const int* __restrict__ rows,
                                                    const int* __restrict__ cols,
                                                    const float* __restrict__ vals,
                                                    u32* __restrict__ bcol,
                                                    u16* __restrict__ bval,
                                                    u32* __restrict__ dir, int E, int B) {
  __shared__ u32 hist[NBK];    // counts -> running ptr
  __shared__ u32 starts[NBK];  // exclusive scan
  __shared__ u32 wtot[4];
  __shared__ u32 s_lo[SC_C];   // 32 KB
  __shared__ u16 s_val[SC_C];  // 16 KB   (total LDS 63.5 KB)
  int tid = threadIdx.x;
  int wg = blockIdx.x;
  int base = wg * SC_C;
  int tot = min(SC_C, E - base);

  for (int b = tid; b < NBK; b += 256) hist[b] = 0;
  __syncthreads();
  // pass 1: local bucket histogram
  for (int j = tid; j < tot; j += 256) {
    atomicAdd(&hist[((u32)rows[base + j]) >> NB_SH], 1u);
  }
  __syncthreads();
  scan_nbk(hist, starts, wtot);
  for (int b = tid; b < NBK; b += 256) hist[b] = starts[b];  // running ptrs
  __syncthreads();
  // pass 2: rank final records into bucket-grouped LDS (all reads coalesced)
  for (int j = tid; j < tot; j += 256) {
    u32 r = (u32)rows[base + j];
    u32 bk = r >> NB_SH;
    u32 p = atomicAdd(&hist[bk], 1u);
    s_lo[p] = ((r & 63u) << 26) | ((u32)cols[base + j] << 8);
    s_val[p] = (u16)f32_to_bf16_rne(vals[base + j]);
  }
  __syncthreads();
  // flush: pure streaming writes to own region
  for (int i = tid; i < tot; i += 256) {
    bcol[(size_t)base + i] = s_lo[i];
    bval[(size_t)base + i] = s_val[i];
  }
  // directory row (coalesced): start/cnt per bucket within this region
  for (int b = tid; b < B; b += 256) {
    dir[(size_t)wg * B + b] = (starts[b] << 16) | (hist[b] - starts[b]);
  }
}

// One WG per 64-node bucket. Gathers its segments via the directory (9-step
// fixed-depth binary search over the 391-segment scan), then identical to R5:
// node counting-sort in LDS, flat walk with depth-8 gather pipeline, direct
// relu'd global flush.
__global__ __launch_bounds__(256) void agg_bucket(const u32* __restrict__ bcol,
                                                  const u16* __restrict__ bval,
                                                  const u32* __restrict__ dir,
                                                  const u32* __restrict__ h,
                                                  float* __restrict__ out, int N,
                                                  int nsc, int B) {
  __shared__ u64 s_rec[AGG_CAP];  // 20 KB
  __shared__ u32 segdir[512], segdst[512];
  __shared__ u32 cnt[AGG_NB], excl[AGG_NB], ptr[AGG_NB], wtot[4];
  int tid = threadIdx.x, lane = tid & 63, wave = tid >> 6;
  int b = blockIdx.x;
  int nodeBase = b << NB_SH;
  int lane4 = lane * 4;
  const char* hb = (const char*)h;

  // load my directory column + zero node counters
  for (int w = tid; w < nsc; w += 256) segdir[w] = dir[(size_t)w * B + b];
  if (tid < AGG_NB) cnt[tid] = 0;
  __syncthreads();
  // exclusive scan of segment counts (2 elements per thread, 512 logical)
  {
    int e0 = 2 * tid, e1 = e0 + 1;
    u32 c0 = (e0 < nsc) ? (segdir[e0] & 0xffffu) : 0u;
    u32 c1 = (e1 < nsc) ? (segdir[e1] & 0xffffu) : 0u;
    u32 s = c0 + c1, inc = s;
#pragma unroll
    for (int d = 1; d < 64; d <<= 1) {
      u32 t = __shfl_up(inc, d, 64);
      if (lane >= d) inc += t;
    }
    if (lane == 63) wtot[wave] = inc;
    __syncthreads();
    u32 wbase = 0;
    for (int w = 0; w < wave; ++w) wbase += wtot[w];
    u32 ex = wbase + inc - s;
    segdst[e0] = ex;
    segdst[e1] = ex + c0;
    __syncthreads();
  }
  int T = (int)(wtot[0] + wtot[1] + wtot[2] + wtot[3]);

  if (T <= AGG_CAP) {
    // pass A: stage records via segment search + node histogram
    u32 rlo[10], rv[10];
#pragma unroll
    for (int k = 0; k < 10; ++k) {
      int g = tid + 256 * k;
      rlo[k] = 0;
      rv[k] = 0;
      if (g < T) {
        int lo = 0, hi = nsc - 1;  // largest w with segdst[w] <= g (fixed depth)
        while (lo < hi) {
          int mid = (lo + hi + 1) >> 1;
          if (segdst[mid] <= (u32)g) lo = mid; else hi = mid - 1;
        }
        u32 dv = segdir[lo];
        u32 src = (u32)lo * SC_C + (dv >> 16) + ((u32)g - segdst[lo]);
        rlo[k] = bcol[src];
        rv[k] = bval[src];
        atomicAdd(&cnt[rlo[k] >> 26], 1u);
      }
    }
    __syncthreads();
    if (tid < 64) {
      u32 c = cnt[tid], inc = c;
#pragma unroll
      for (int d = 1; d < 64; d <<= 1) {
        u32 t = __shfl_up(inc, d, 64);
        if (lane >= d) inc += t;
      }
      excl[tid] = inc - c;
      ptr[tid] = inc - c;
    }
    __syncthreads();
    // pass B: rank into node-sorted LDS staging (u64 records)
#pragma unroll
    for (int k = 0; k < 10; ++k) {
      int g = tid + 256 * k;
      if (g < T) {
        u32 p = atomicAdd(&ptr[rlo[k] >> 26], 1u);
        s_rec[p] = ((u64)(rv[k] << 16) << 32) | rlo[k];
      }
    }
    __syncthreads();
    // pass C: flat walk of my wave's contiguous segment, depth-8 pipeline
    int wbeg = (int)excl[wave * 16];
    int wend = (int)ptr[wave * 16 + 15];
    float a0 = 0.f, a1 = 0.f;
    int curn = -1;
    for (int e = wbeg; e < wend; e += 8) {
      u32 lo8[8];
      float v8[8];
      u32 hd[8];
#pragma unroll
      for (int g = 0; g < 8; ++g) {
        int ee = e + g;
        bool act = ee < wend;
        u64 r = s_rec[act ? ee : (wend - 1)];  // wave-uniform broadcast read
        lo8[g] = (u32)r;
        v8[g] = act ? __uint_as_float((u32)(r >> 32)) : 0.f;
      }
#pragma unroll
      for (int g = 0; g < 8; ++g) {
        hd[g] = *(const u32*)(hb + ((lo8[g] & 0x01FFFF00u) + lane4));
      }
#pragma unroll
      for (int g = 0; g < 8; ++g) {
        int nid = __builtin_amdgcn_readfirstlane((int)(lo8[g] >> 26));
        if (nid != curn) {  // scalar branch, once per run
          if (curn >= 0) {
            float2 o = make_float2(fmaxf(a0, 0.f), fmaxf(a1, 0.f));
            *(float2*)(out + (size_t)(nodeBase + curn) * DIM + 2 * lane) = o;
          }
          curn = nid;
          a0 = 0.f;
          a1 = 0.f;
        }
        float v = v8[g];
        a0 += v * bf16_to_f32(hd[g] & 0xffffu);
        a1 += v * bf16_to_f32(hd[g] >> 16);
      }
    }
    if (curn >= 0) {
      float2 o = make_float2(fmaxf(a0, 0.f), fmaxf(a1, 0.f));
      *(float2*)(out + (size_t)(nodeBase + curn) * DIM + 2 * lane) = o;
    }
    // epilogue: zero rows for nodes with no edges
    for (int nn = 0; nn < 16; ++nn) {
      int nl = wave * 16 + nn;
      int node = nodeBase + nl;
      if (cnt[nl] == 0 && node < N) {
        *(float2*)(out + (size_t)node * DIM + 2 * lane) = make_float2(0.f, 0.f);
      }
    }
  } else {
    // Guaranteed-correct fallback (statistically unreachable): per-node scan
    // of all this bucket's segments.
    for (int nn = 0; nn < 16; ++nn) {
      int nl = wave * 16 + nn;
      int node = nodeBase + nl;
      if (node >= N) continue;
      float a0 = 0.f, a1 = 0.f;
      for (int w = 0; w < nsc; ++w) {
        u32 dv = segdir[w];
        int sc = (int)(dv & 0xffffu);
        u32 so = dv >> 16;
        for (int r = 0; r < sc; ++r) {
          u32 lo = bcol[(size_t)w * SC_C + so + r];
          if ((int)(lo >> 26) == nl) {
            u32 d = *(const u32*)(hb + ((lo & 0x01FFFF00u) + lane4));
            float v = bf16_to_f32(bval[(size_t)w * SC_C + so + r]);
            a0 += v * bf16_to_f32(d & 0xffffu);
            a1 += v * bf16_to_f32(d >> 16);
          }
        }
      }
      *(float2*)(out + (size_t)node * DIM + 2 * lane) =
          make_float2(fmaxf(a0, 0.f), fmaxf(a1, 0.f));
    }
  }
}

extern "C" void kernel_launch(void* const* d_in, const int* in_sizes, int n_in,
                              void* d_out, int out_size, void* d_ws, size_t ws_size,
                              hipStream_t stream) {
  const float* x    = (const float*)d_in[0];  // fp32 [N,128]
  const int*   rows = (const int*)d_in[1];    // int32 [E]
  const int*   cols = (const int*)d_in[2];    // int32 [E]
  const float* vals = (const float*)d_in[3];  // fp32 [E]
  const float* W    = (const float*)d_in[4];  // fp32 [128,128]

  const int N = in_sizes[0] / DIM;  // 100000
  const int E = in_sizes[1];        // 3200000
  const int B = (N + AGG_NB - 1) / AGG_NB;  // 1563 buckets
  const int nsc = (E + SC_C - 1) / SC_C;    // 391 regions

  char* wsb = (char*)d_ws;
  size_t o = 0;
  u16* h = (u16*)wsb;            o += (size_t)N * DIM * sizeof(u16);      // 25.6 MB
  u32* bcol = (u32*)(wsb + o);   o += (size_t)nsc * SC_C * sizeof(u32);   // 12.8 MB
  u16* bval = (u16*)(wsb + o);   o += (size_t)nsc * SC_C * sizeof(u16);   // 6.4 MB
  u32* dir  = (u32*)(wsb + o);   o += (size_t)nsc * B * sizeof(u32);      // 2.4 MB

  gemm_mfma<<<256, 256, 0, stream>>>(x, W, h, N);
  sort_scatter<<<nsc, 256, 0, stream>>>(rows, cols, vals, bcol, bval, dir, E, B);
  agg_bucket<<<B, 256, 0, stream>>>(bcol, bval, dir, (const u32*)h,
                                    (float*)d_out, N, nsc, B);
}